// Round 4
// baseline (332.825 us; speedup 1.0000x reference)
//
#include <hip/hip_runtime.h>
#include <stdint.h>

// ---------------------------------------------------------------------------
// MultiHeadedAttention: B=8, N=1024, E=512, H=8, D_K=64
// Round 4: 16-row attention waves (2x wave count -> 50% occupancy);
// m97-style 128x128 pure-DMA GEMMs (pre-cast bf16 A); Q pre-scaled by
// 0.125/ln2 so attn exp is a bare v_exp_f32.
// ---------------------------------------------------------------------------

typedef __attribute__((ext_vector_type(8))) short short8;
typedef __attribute__((ext_vector_type(4))) float floatx4;

#define MFMA16(a, b, c) __builtin_amdgcn_mfma_f32_16x16x32_bf16((a), (b), (c), 0, 0, 0)
#define QSCALE 0.1803368801111362f   // 0.125 / ln(2): exp(s/8) = exp2(s*QSCALE)

static __device__ __forceinline__ unsigned short f2bf(float f) {
  union { float f; unsigned u; } v; v.f = f;
  unsigned r = v.u + 0x7fffu + ((v.u >> 16) & 1u);   // RNE
  return (unsigned short)(r >> 16);
}

// async global->LDS 16B/lane. LDS dest is wave-uniform base + lane*16 (m104).
static __device__ __forceinline__ void gload_lds16(const void* g, void* l) {
  __builtin_amdgcn_global_load_lds((const __attribute__((address_space(1))) unsigned int*)g,
                                   (__attribute__((address_space(3))) unsigned int*)l,
                                   16, 0, 0);
}
// chunk swizzle for unpadded 32-elem-wide bf16 LDS tiles (GEMM staging).
static __device__ __forceinline__ int xsw(int row) { return (row & 3) ^ ((row >> 2) & 3); }

// ---------------- fused fp32->bf16 cast: q,k,v + 4 weight matrices ----------------
__global__ void cast_all(const float* __restrict__ q, const float* __restrict__ k,
                         const float* __restrict__ v,
                         const float* __restrict__ wq, const float* __restrict__ wk,
                         const float* __restrict__ wv, const float* __restrict__ wo,
                         unsigned short* __restrict__ qb, unsigned short* __restrict__ kb,
                         unsigned short* __restrict__ vb,
                         unsigned short* __restrict__ wq16, unsigned short* __restrict__ wk16,
                         unsigned short* __restrict__ wv16, unsigned short* __restrict__ wo16) {
  int i = blockIdx.x * blockDim.x + threadIdx.x;   // 0 .. 3407871 (float4 units)
  const float* s; unsigned short* d; int loc;
  if (i < 3145728) {            // 3 x 1048576 float4 (q,k,v)
    int w = i >> 20; loc = i & 1048575;
    s = (w == 0) ? q : (w == 1) ? k : v;
    d = (w == 0) ? qb : (w == 1) ? kb : vb;
  } else {                      // 4 x 65536 float4 (weights)
    int j = i - 3145728; int w = j >> 16; loc = j & 65535;
    s = (w == 0) ? wq : (w == 1) ? wk : (w == 2) ? wv : wo;
    d = (w == 0) ? wq16 : (w == 1) ? wk16 : (w == 2) ? wv16 : wo16;
  }
  float4 vv = ((const float4*)s)[loc];
  ushort4 o;
  o.x = f2bf(vv.x); o.y = f2bf(vv.y); o.z = f2bf(vv.z); o.w = f2bf(vv.w);
  ((ushort4*)d)[loc] = o;
}

// ---------------- dist+mask -> permuted code bytes ----------------
// allowed(h) <=> h >= code (DIST_BAR ascending). 0 on row/col 0; 9 if mask==0.
// Layout matches attn exp-epilogue: codesP[(((b*32+rg)*8+kt)*64+lane)*64 + st*32 + ci*4 + r]
// with row = rg*32 + st*16 + q*4 + r, col = kt*128 + ci*16 + c, lane = q*16+c.
__global__ void codes_kernel(const float* __restrict__ dist, const int* __restrict__ mask,
                             unsigned char* __restrict__ codesP) {
  int t = blockIdx.x * blockDim.x + threadIdx.x;   // over B*N*N/4
  int flat = t << 2;
  int b = flat >> 20;
  int rem = flat & ((1 << 20) - 1);
  int row = rem >> 10;
  int col0 = rem & 1023;
  float4 d4 = ((const float4*)dist)[t];
  int4 m4 = ((const int4*)mask)[t];
  float dv[4] = {d4.x, d4.y, d4.z, d4.w};
  int mv[4] = {m4.x, m4.y, m4.z, m4.w};
  int rg = row >> 5;
  int st = (row >> 4) & 1;
  int qq = (row >> 2) & 3;
  int r = row & 3;
  size_t rowbase = (size_t)(b * 32 + rg) * 32768;
  int sub = st * 32 + r;
#pragma unroll
  for (int u = 0; u < 4; u++) {
    int col = col0 + u;
    float d = dv[u];
    int hmin = (d >= 0.2f) + (d >= 0.3f) + (d >= 0.4f) + (d >= 0.5f) +
               (d >= 0.6f) + (d >= 0.7f) + (d >= 0.8f) + (d >= 0.9f);
    unsigned char cc = (unsigned char)hmin;
    if (row == 0 || col == 0) cc = 0;
    if (mv[u] == 0) cc = 9;
    int kt = col >> 7, ci = (col >> 4) & 7, c = col & 15;
    int lane = qq * 16 + c;
    codesP[rowbase + (size_t)kt * 4096 + lane * 64 + sub + ci * 4] = cc;
  }
}

// ---------------- fused QKV projection GEMM (m97-style 128x128, BK=32) ----------------
// C[m][n] = sum_k A[m][k]*W[n][k] + bias[n];  M=8192, N=512, K=512. All bf16 DMA.
// z=0: Qh [bh][n][d] scaled by QSCALE; z=1: Kh [bh][n][d]; z=2: Vt [bh][d][n].
__global__ __launch_bounds__(256) void qkv_gemm(
    const unsigned short* __restrict__ Aq, const unsigned short* __restrict__ Ak,
    const unsigned short* __restrict__ Av,
    const unsigned short* __restrict__ Wqp, const unsigned short* __restrict__ Wkp,
    const unsigned short* __restrict__ Wvp,
    const float* __restrict__ bq, const float* __restrict__ bk, const float* __restrict__ bv,
    unsigned short* __restrict__ Qh, unsigned short* __restrict__ Kh,
    unsigned short* __restrict__ Vt) {
  const int z = blockIdx.z;
  const unsigned short* A = (z == 0) ? Aq : (z == 1) ? Ak : Av;
  const unsigned short* W = (z == 0) ? Wqp : (z == 1) ? Wkp : Wvp;
  const float* bias = (z == 0) ? bq : (z == 1) ? bk : bv;
  unsigned short* O = (z == 0) ? Qh : (z == 1) ? Kh : Vt;

  __shared__ __align__(16) short As[128 * 32];
  __shared__ __align__(16) short Bs[128 * 32];
  const int tid = threadIdx.x;
  const int lane = tid & 63;
  const int wave = tid >> 6;
  const int c = lane & 15;
  const int q = lane >> 4;
  const int m0 = blockIdx.x * 128;
  const int n0 = blockIdx.y * 128;
  const int wr = (wave >> 1) * 64;
  const int wc = (wave & 1) * 64;

  floatx4 acc[4][4];
#pragma unroll
  for (int i = 0; i < 4; i++)
#pragma unroll
    for (int j = 0; j < 4; j++) acc[i][j] = (floatx4)(0.0f);

  for (int k0 = 0; k0 < 512; k0 += 32) {
    __syncthreads();
#pragma unroll
    for (int it = 0; it < 2; it++) {
      int slot = wave * 128 + it * 64 + lane;
      int row = slot >> 2, ch = slot & 3;
      int g = ch ^ xsw(row);
      gload_lds16(A + (size_t)(m0 + row) * 512 + k0 + g * 8, &As[(wave * 128 + it * 64) * 8]);
      gload_lds16(W + (size_t)(n0 + row) * 512 + k0 + g * 8, &Bs[(wave * 128 + it * 64) * 8]);
    }
    __syncthreads();

    short8 af[4], bfv[4];
#pragma unroll
    for (int i = 0; i < 4; i++) {
      int row = wr + i * 16 + c;
      af[i] = *(const short8*)(&As[row * 32 + (q ^ xsw(row)) * 8]);
    }
#pragma unroll
    for (int j = 0; j < 4; j++) {
      int row = wc + j * 16 + c;
      bfv[j] = *(const short8*)(&Bs[row * 32 + (q ^ xsw(row)) * 8]);
    }
#pragma unroll
    for (int i = 0; i < 4; i++)
#pragma unroll
      for (int j = 0; j < 4; j++)
        acc[i][j] = MFMA16(af[i], bfv[j], acc[i][j]);
  }

  const float scale = (z == 0) ? QSCALE : 1.0f;
#pragma unroll
  for (int i = 0; i < 4; i++) {
    int gm0 = m0 + wr + i * 16 + q * 4;
#pragma unroll
    for (int j = 0; j < 4; j++) {
      int gn = n0 + wc + j * 16 + c;
      float bb = bias[gn];
      int h = gn >> 6, d = gn & 63;
      if (z == 2) {
        int b = gm0 >> 10, n = gm0 & 1023;
        ushort4 pk;
#pragma unroll
        for (int r = 0; r < 4; r++) pk[r] = f2bf(acc[i][j][r] + bb);
        *(ushort4*)(&Vt[(((size_t)(b * 8 + h) * 64 + d) << 10) + n]) = pk;  // [bh][d][n]
      } else {
#pragma unroll
        for (int r = 0; r < 4; r++) {
          int m = gm0 + r;
          int b = m >> 10, n = m & 1023;
          O[((((size_t)(b * 8 + h)) << 10) + n) * 64 + d] = f2bf((acc[i][j][r] + bb) * scale);
        }
      }
    }
  }
}

// ---------------- output projection GEMM (128x64 tile, bf16 A, fp32 out) ----------------
__global__ __launch_bounds__(256) void out_gemm(const unsigned short* __restrict__ A,
                                                const unsigned short* __restrict__ W,
                                                const float* __restrict__ bias,
                                                float* __restrict__ Out) {
  __shared__ __align__(16) short As[128 * 32];
  __shared__ __align__(16) short Bs[64 * 32];
  const int tid = threadIdx.x;
  const int lane = tid & 63;
  const int wave = tid >> 6;
  const int c = lane & 15;
  const int q = lane >> 4;
  const int m0 = blockIdx.x * 128;
  const int n0 = blockIdx.y * 64;
  const int wr = (wave >> 1) * 64;
  const int wc = (wave & 1) * 32;

  floatx4 acc[4][2];
#pragma unroll
  for (int i = 0; i < 4; i++)
#pragma unroll
    for (int j = 0; j < 2; j++) acc[i][j] = (floatx4)(0.0f);

  for (int k0 = 0; k0 < 512; k0 += 32) {
    __syncthreads();
#pragma unroll
    for (int it = 0; it < 2; it++) {
      int slot = wave * 128 + it * 64 + lane;
      int row = slot >> 2, ch = slot & 3;
      int g = ch ^ xsw(row);
      gload_lds16(A + (size_t)(m0 + row) * 512 + k0 + g * 8, &As[(wave * 128 + it * 64) * 8]);
    }
    {
      int slot = wave * 64 + lane;
      int row = slot >> 2, ch = slot & 3;
      int g = ch ^ xsw(row);
      gload_lds16(W + (size_t)(n0 + row) * 512 + k0 + g * 8, &Bs[(wave * 64) * 8]);
    }
    __syncthreads();

    short8 af[4], bfv[2];
#pragma unroll
    for (int i = 0; i < 4; i++) {
      int row = wr + i * 16 + c;
      af[i] = *(const short8*)(&As[row * 32 + (q ^ xsw(row)) * 8]);
    }
#pragma unroll
    for (int j = 0; j < 2; j++) {
      int row = wc + j * 16 + c;
      bfv[j] = *(const short8*)(&Bs[row * 32 + (q ^ xsw(row)) * 8]);
    }
#pragma unroll
    for (int i = 0; i < 4; i++)
#pragma unroll
      for (int j = 0; j < 2; j++)
        acc[i][j] = MFMA16(af[i], bfv[j], acc[i][j]);
  }

#pragma unroll
  for (int i = 0; i < 4; i++) {
    int gm0 = m0 + wr + i * 16 + q * 4;
#pragma unroll
    for (int j = 0; j < 2; j++) {
      int gn = n0 + wc + j * 16 + c;
      float bb = bias[gn];
#pragma unroll
      for (int r = 0; r < 4; r++)
        Out[(size_t)(gm0 + r) * 512 + gn] = acc[i][j][r] + bb;
    }
  }
}

// ---------------- barrier-free flash attention, 16-row waves ----------------
// Wave w of WG (gx, bh) owns q-rows [gx*64 + w*16, +16). 4096 waves total
// (2x round 3) -> 16 waves/CU. Per 128-col K tile: S = QK^T (Q pre-scaled) ->
// exp2 -> wave-private LDS P -> PV. No __syncthreads anywhere.
__global__ __launch_bounds__(256) void attn_kernel(const unsigned short* __restrict__ Qh,
                                                   const unsigned short* __restrict__ Kh,
                                                   const unsigned short* __restrict__ Vt,
                                                   const unsigned char* __restrict__ codesP,
                                                   unsigned short* __restrict__ AO) {
  __shared__ __align__(16) unsigned short P[4][16 * 132];   // 16.5 KB, wave-private
  const int tid = threadIdx.x;
  const int lane = tid & 63;
  const int wave = tid >> 6;
  const int c = lane & 15;
  const int q = lane >> 4;
  const int bh = blockIdx.y;
  const int b = bh >> 3;
  const int h = bh & 7;
  const size_t base = (size_t)bh << 16;
  const int rbase = blockIdx.x * 64 + wave * 16;
  const int rg = rbase >> 5;
  const int st = (rbase >> 4) & 1;
  unsigned short* Pw = &P[wave][0];

  // Q A-fragments (16 rows), pre-scaled by QSCALE at projection time
  short8 aq[2];
#pragma unroll
  for (int kk = 0; kk < 2; kk++)
    aq[kk] = *(const short8*)(Qh + base + (size_t)(rbase + c) * 64 + kk * 32 + q * 8);

  const unsigned char* cbt = codesP + (size_t)(b * 32 + rg) * 32768 + lane * 64 + st * 32;
  const unsigned short* Kb = Kh + base;
  const unsigned short* Vb = Vt + base;

  float rs[4] = {0.0f, 0.0f, 0.0f, 0.0f};
  floatx4 o[4];
#pragma unroll
  for (int ci = 0; ci < 4; ci++) o[ci] = (floatx4)(0.0f);

  for (int kt = 0; kt < 8; kt++) {
    // ---- QK^T over this wave's 16 rows x 128 kv cols ----
    const unsigned short* Kt = Kb + (size_t)kt * 128 * 64;
    floatx4 s[8];
#pragma unroll
    for (int ci = 0; ci < 8; ci++) s[ci] = (floatx4)(0.0f);
#pragma unroll
    for (int ci = 0; ci < 8; ci++)
#pragma unroll
      for (int kk = 0; kk < 2; kk++) {
        short8 bk = *(const short8*)(Kt + (size_t)(ci * 16 + c) * 64 + kk * 32 + q * 8);
        s[ci] = MFMA16(aq[kk], bk, s[ci]);
      }
    // ---- codes: 32 bytes/lane, pre-permuted, 2 dwordx4 loads ----
    const unsigned char* cp = cbt + (size_t)kt * 4096;
    uint4 w0 = *(const uint4*)(cp);
    uint4 w1 = *(const uint4*)(cp + 16);
    unsigned cv[8] = {w0.x, w0.y, w0.z, w0.w, w1.x, w1.y, w1.z, w1.w};
    // ---- exp epilogue -> wave-private P + register row sums ----
#pragma unroll
    for (int ci = 0; ci < 8; ci++)
#pragma unroll
      for (int r = 0; r < 4; r++) {
        int code = (cv[ci] >> (r * 8)) & 0xff;
        float e = (h >= code) ? exp2f(s[ci][r]) : 0.0f;
        rs[r] += e;
        Pw[(q * 4 + r) * 132 + ci * 16 + c] = f2bf(e);
      }
    // ---- PV (wave-local LDS readback, lgkmcnt ordering only) ----
#pragma unroll
    for (int ch = 0; ch < 4; ch++) {
      short8 ap = *(const short8*)(&Pw[(size_t)c * 132 + ch * 32 + q * 8]);
#pragma unroll
      for (int ci = 0; ci < 4; ci++) {
        short8 bv = *(const short8*)(Vb + (size_t)(ci * 16 + c) * 1024 + kt * 128 + ch * 32 + q * 8);
        o[ci] = MFMA16(ap, bv, o[ci]);
      }
    }
  }

  // ---- normalize + write ----
  float inv[4];
#pragma unroll
  for (int r = 0; r < 4; r++) {
    float v = rs[r];
    v += __shfl_xor(v, 1); v += __shfl_xor(v, 2);
    v += __shfl_xor(v, 4); v += __shfl_xor(v, 8);
    inv[r] = 1.0f / v;
  }
#pragma unroll
  for (int r = 0; r < 4; r++) {
    int n = rbase + q * 4 + r;
    size_t ob = ((size_t)((b << 10) + n)) * 512 + h * 64;
#pragma unroll
    for (int ci = 0; ci < 4; ci++)
      AO[ob + ci * 16 + c] = f2bf(o[ci][r] * inv[r]);
  }
}

// ---------------- launcher ----------------
extern "C" void kernel_launch(void* const* d_in, const int* in_sizes, int n_in,
                              void* d_out, int out_size, void* d_ws, size_t ws_size,
                              hipStream_t stream) {
  const float* query = (const float*)d_in[0];
  const float* key_  = (const float*)d_in[1];
  const float* value = (const float*)d_in[2];
  const float* dist  = (const float*)d_in[3];
  const int*   mask  = (const int*)d_in[4];
  const float* Wq = (const float*)d_in[5];
  const float* bq = (const float*)d_in[6];
  const float* Wk = (const float*)d_in[7];
  const float* bk = (const float*)d_in[8];
  const float* Wv = (const float*)d_in[9];
  const float* bv = (const float*)d_in[10];
  const float* Wo = (const float*)d_in[11];
  const float* bo = (const float*)d_in[12];

  char* ws = (char*)d_ws;
  size_t off = 0;
  auto alloc = [&](size_t bytes) -> char* {
    char* p = ws + off;
    off += (bytes + 255) & ~(size_t)255;
    return p;
  };
  const size_t NQKV = 8192ull * 512;
  unsigned short* qb   = (unsigned short*)alloc(NQKV * 2);
  unsigned short* kb   = (unsigned short*)alloc(NQKV * 2);
  unsigned short* vb   = (unsigned short*)alloc(NQKV * 2);
  unsigned short* wq16 = (unsigned short*)alloc(512ull * 512 * 2);
  unsigned short* wk16 = (unsigned short*)alloc(512ull * 512 * 2);
  unsigned short* wv16 = (unsigned short*)alloc(512ull * 512 * 2);
  unsigned short* wo16 = (unsigned short*)alloc(512ull * 512 * 2);
  unsigned short* Qh = (unsigned short*)alloc(NQKV * 2);
  unsigned short* Kh = (unsigned short*)alloc(NQKV * 2);
  unsigned short* Vt = (unsigned short*)alloc(NQKV * 2);
  unsigned short* AO = (unsigned short*)alloc(NQKV * 2);
  unsigned char*  codesP = (unsigned char*)alloc(8ull * 1024 * 1024);

  cast_all<<<13312, 256, 0, stream>>>(query, key_, value, Wq, Wk, Wv, Wo,
                                      qb, kb, vb, wq16, wk16, wv16, wo16);
  codes_kernel<<<8192, 256, 0, stream>>>(dist, mask, codesP);
  qkv_gemm<<<dim3(64, 4, 3), 256, 0, stream>>>(qb, kb, vb, wq16, wk16, wv16,
                                               bq, bk, bv, Qh, Kh, Vt);
  attn_kernel<<<dim3(16, 64), 256, 0, stream>>>(Qh, Kh, Vt, codesP, AO);
  out_gemm<<<dim3(64, 8), 256, 0, stream>>>(AO, wo16, bo, (float*)d_out);
}

// Round 5
// 296.541 us; speedup vs baseline: 1.1224x; 1.1224x over previous
//
#include <hip/hip_runtime.h>
#include <stdint.h>

// ---------------------------------------------------------------------------
// MultiHeadedAttention: B=8, N=1024, E=512, H=8, D_K=64
// Round 5: attn = 32-row waves (r3 per-wave efficiency) x kv-split (2x waves);
// qkv_gemm z=0/1 operand-swapped for packed ushort4 epilogue stores;
// cast+codes merged into one prep kernel.
// ---------------------------------------------------------------------------

typedef __attribute__((ext_vector_type(8))) short short8;
typedef __attribute__((ext_vector_type(4))) float floatx4;

#define MFMA16(a, b, c) __builtin_amdgcn_mfma_f32_16x16x32_bf16((a), (b), (c), 0, 0, 0)
#define QSCALE 0.1803368801111362f   // 0.125 / ln(2): exp(s/8) = exp2(s*QSCALE)

static __device__ __forceinline__ unsigned short f2bf(float f) {
  union { float f; unsigned u; } v; v.f = f;
  unsigned r = v.u + 0x7fffu + ((v.u >> 16) & 1u);   // RNE
  return (unsigned short)(r >> 16);
}

// async global->LDS 16B/lane. LDS dest is wave-uniform base + lane*16 (m104).
static __device__ __forceinline__ void gload_lds16(const void* g, void* l) {
  __builtin_amdgcn_global_load_lds((const __attribute__((address_space(1))) unsigned int*)g,
                                   (__attribute__((address_space(3))) unsigned int*)l,
                                   16, 0, 0);
}
// chunk swizzle for unpadded 32-elem-wide bf16 LDS tiles (GEMM staging).
static __device__ __forceinline__ int xsw(int row) { return (row & 3) ^ ((row >> 2) & 3); }

// ---------------- prep: fp32->bf16 casts + dist/mask -> permuted codes ----------------
// Blocks [0, 13312): cast q,k,v + 4 weights (float4 units).
// Blocks [13312, 21504): codes. allowed(h) <=> h >= code; 0 on row/col 0; 9 if mask==0.
// codesP layout matches attn exp-epilogue:
//   codesP[(((b*32+rg)*8+kt)*64+lane)*64 + st*32 + ci*4 + r]
// with row = rg*32 + st*16 + q*4 + r, col = kt*128 + ci*16 + c, lane = q*16+c.
__global__ void prep_kernel(const float* __restrict__ q, const float* __restrict__ k,
                            const float* __restrict__ v,
                            const float* __restrict__ wq, const float* __restrict__ wk,
                            const float* __restrict__ wv, const float* __restrict__ wo,
                            const float* __restrict__ dist, const int* __restrict__ mask,
                            unsigned short* __restrict__ qb, unsigned short* __restrict__ kb,
                            unsigned short* __restrict__ vb,
                            unsigned short* __restrict__ wq16, unsigned short* __restrict__ wk16,
                            unsigned short* __restrict__ wv16, unsigned short* __restrict__ wo16,
                            unsigned char* __restrict__ codesP) {
  int gb = blockIdx.x;
  if (gb < 13312) {
    int i = gb * 256 + threadIdx.x;   // float4 units
    const float* s; unsigned short* d; int loc;
    if (i < 3145728) {
      int w = i >> 20; loc = i & 1048575;
      s = (w == 0) ? q : (w == 1) ? k : v;
      d = (w == 0) ? qb : (w == 1) ? kb : vb;
    } else {
      int j = i - 3145728; int w = j >> 16; loc = j & 65535;
      s = (w == 0) ? wq : (w == 1) ? wk : (w == 2) ? wv : wo;
      d = (w == 0) ? wq16 : (w == 1) ? wk16 : (w == 2) ? wv16 : wo16;
    }
    float4 vv = ((const float4*)s)[loc];
    ushort4 o;
    o.x = f2bf(vv.x); o.y = f2bf(vv.y); o.z = f2bf(vv.z); o.w = f2bf(vv.w);
    ((ushort4*)d)[loc] = o;
  } else {
    int t = (gb - 13312) * 256 + threadIdx.x;   // over B*N*N/4
    int flat = t << 2;
    int b = flat >> 20;
    int rem = flat & ((1 << 20) - 1);
    int row = rem >> 10;
    int col0 = rem & 1023;
    float4 d4 = ((const float4*)dist)[t];
    int4 m4 = ((const int4*)mask)[t];
    float dv[4] = {d4.x, d4.y, d4.z, d4.w};
    int mv[4] = {m4.x, m4.y, m4.z, m4.w};
    int rg = row >> 5;
    int st = (row >> 4) & 1;
    int qq = (row >> 2) & 3;
    int r = row & 3;
    size_t rowbase = (size_t)(b * 32 + rg) * 32768;
    int sub = st * 32 + r;
#pragma unroll
    for (int u = 0; u < 4; u++) {
      int col = col0 + u;
      float d = dv[u];
      int hmin = (d >= 0.2f) + (d >= 0.3f) + (d >= 0.4f) + (d >= 0.5f) +
                 (d >= 0.6f) + (d >= 0.7f) + (d >= 0.8f) + (d >= 0.9f);
      unsigned char cc = (unsigned char)hmin;
      if (row == 0 || col == 0) cc = 0;
      if (mv[u] == 0) cc = 9;
      int kt = col >> 7, ci = (col >> 4) & 7, c = col & 15;
      int lane = qq * 16 + c;
      codesP[rowbase + (size_t)kt * 4096 + lane * 64 + sub + ci * 4] = cc;
    }
  }
}

// ---------------- fused QKV projection GEMM (128x128 tile, BK=32, DMA) ----------------
// C[t][f] = sum_k X[t][k]*W[f][k] + bias[f];  T=8192, F=512, K=512.
// z=0: Qh [bh][n][d] * QSCALE  (operand-swapped: feature in D-reg quad -> ushort4 pack)
// z=1: Kh [bh][n][d]           (same)
// z=2: Vt [bh][d][n]           (normal orientation: token in D-reg quad -> ushort4 pack)
__global__ __launch_bounds__(256) void qkv_gemm(
    const unsigned short* __restrict__ Xq, const unsigned short* __restrict__ Xk,
    const unsigned short* __restrict__ Xv,
    const unsigned short* __restrict__ Wqp, const unsigned short* __restrict__ Wkp,
    const unsigned short* __restrict__ Wvp,
    const float* __restrict__ bq, const float* __restrict__ bk, const float* __restrict__ bv,
    unsigned short* __restrict__ Qh, unsigned short* __restrict__ Kh,
    unsigned short* __restrict__ Vt) {
  const int z = blockIdx.z;
  const unsigned short* X = (z == 0) ? Xq : (z == 1) ? Xk : Xv;
  const unsigned short* W = (z == 0) ? Wqp : (z == 1) ? Wkp : Wvp;
  const float* bias = (z == 0) ? bq : (z == 1) ? bk : bv;
  unsigned short* O = (z == 0) ? Qh : (z == 1) ? Kh : Vt;

  __shared__ __align__(16) short Xs[128 * 32];
  __shared__ __align__(16) short Ws[128 * 32];
  const int tid = threadIdx.x;
  const int lane = tid & 63;
  const int wave = tid >> 6;
  const int c = lane & 15;
  const int q = lane >> 4;
  const int m0 = blockIdx.x * 128;   // token base
  const int n0 = blockIdx.y * 128;   // feature base
  const int wr = (wave >> 1) * 64;
  const int wc = (wave & 1) * 64;

  floatx4 acc[4][4];
#pragma unroll
  for (int i = 0; i < 4; i++)
#pragma unroll
    for (int j = 0; j < 4; j++) acc[i][j] = (floatx4)(0.0f);

  for (int k0 = 0; k0 < 512; k0 += 32) {
    __syncthreads();
#pragma unroll
    for (int it = 0; it < 2; it++) {
      int slot = wave * 128 + it * 64 + lane;
      int row = slot >> 2, ch = slot & 3;
      int g = ch ^ xsw(row);
      gload_lds16(X + (size_t)(m0 + row) * 512 + k0 + g * 8, &Xs[(wave * 128 + it * 64) * 8]);
      gload_lds16(W + (size_t)(n0 + row) * 512 + k0 + g * 8, &Ws[(wave * 128 + it * 64) * 8]);
    }
    __syncthreads();

    // z<2: A-frag = W rows (features), B-frag = X rows (tokens)  -> D[f][t]
    // z=2: A-frag = X rows (tokens),   B-frag = W rows (features) -> D[t][f]
    const short* Pa = (z == 2) ? Xs : Ws;
    const short* Pb = (z == 2) ? Ws : Xs;
    short8 af[4], bfv[4];
#pragma unroll
    for (int i = 0; i < 4; i++) {
      int row = wr + i * 16 + c;
      af[i] = *(const short8*)(&Pa[row * 32 + (q ^ xsw(row)) * 8]);
    }
#pragma unroll
    for (int j = 0; j < 4; j++) {
      int row = wc + j * 16 + c;
      bfv[j] = *(const short8*)(&Pb[row * 32 + (q ^ xsw(row)) * 8]);
    }
#pragma unroll
    for (int i = 0; i < 4; i++)
#pragma unroll
      for (int j = 0; j < 4; j++)
        acc[i][j] = MFMA16(af[i], bfv[j], acc[i][j]);
  }

  if (z == 2) {
    // D rows = tokens (wr side / m0), cols = features (wc side / n0)
#pragma unroll
    for (int i = 0; i < 4; i++) {
      int gm0 = m0 + wr + i * 16 + q * 4;
      int b = gm0 >> 10, n = gm0 & 1023;
#pragma unroll
      for (int j = 0; j < 4; j++) {
        int gn = n0 + wc + j * 16 + c;
        float bb = bias[gn];
        int h = gn >> 6, d = gn & 63;
        ushort4 pk;
#pragma unroll
        for (int r = 0; r < 4; r++) pk[r] = f2bf(acc[i][j][r] + bb);
        *(ushort4*)(&Vt[(((size_t)(b * 8 + h) * 64 + d) << 10) + n]) = pk;  // [bh][d][n]
      }
    }
  } else {
    const float scale = (z == 0) ? QSCALE : 1.0f;
    // D rows = features (wr side / n0), cols = tokens (wc side / m0)
#pragma unroll
    for (int i = 0; i < 4; i++) {
      int f0 = n0 + wr + i * 16 + q * 4;        // 4 consecutive features
      float4 bb4 = *(const float4*)(bias + f0);
      int h = f0 >> 6, d0 = f0 & 63;            // quad stays within one head
      float bbs[4] = {bb4.x, bb4.y, bb4.z, bb4.w};
#pragma unroll
      for (int j = 0; j < 4; j++) {
        int t = m0 + wc + j * 16 + c;
        int b = t >> 10, n = t & 1023;
        ushort4 pk;
#pragma unroll
        for (int r = 0; r < 4; r++) pk[r] = f2bf((acc[i][j][r] + bbs[r]) * scale);
        *(ushort4*)(&O[((((size_t)(b * 8 + h)) << 10) + n) * 64 + d0]) = pk;  // [bh][n][d]
      }
    }
  }
}

// ---------------- output projection GEMM (128x64 tile, bf16 A, fp32 out) ----------------
__global__ __launch_bounds__(256) void out_gemm(const unsigned short* __restrict__ A,
                                                const unsigned short* __restrict__ W,
                                                const float* __restrict__ bias,
                                                float* __restrict__ Out) {
  __shared__ __align__(16) short As[128 * 32];
  __shared__ __align__(16) short Bs[64 * 32];
  const int tid = threadIdx.x;
  const int lane = tid & 63;
  const int wave = tid >> 6;
  const int c = lane & 15;
  const int q = lane >> 4;
  const int m0 = blockIdx.x * 128;
  const int n0 = blockIdx.y * 64;
  const int wr = (wave >> 1) * 64;
  const int wc = (wave & 1) * 32;

  floatx4 acc[4][2];
#pragma unroll
  for (int i = 0; i < 4; i++)
#pragma unroll
    for (int j = 0; j < 2; j++) acc[i][j] = (floatx4)(0.0f);

  for (int k0 = 0; k0 < 512; k0 += 32) {
    __syncthreads();
#pragma unroll
    for (int it = 0; it < 2; it++) {
      int slot = wave * 128 + it * 64 + lane;
      int row = slot >> 2, ch = slot & 3;
      int g = ch ^ xsw(row);
      gload_lds16(A + (size_t)(m0 + row) * 512 + k0 + g * 8, &As[(wave * 128 + it * 64) * 8]);
    }
    {
      int slot = wave * 64 + lane;
      int row = slot >> 2, ch = slot & 3;
      int g = ch ^ xsw(row);
      gload_lds16(W + (size_t)(n0 + row) * 512 + k0 + g * 8, &Bs[(wave * 64) * 8]);
    }
    __syncthreads();

    short8 af[4], bfv[2];
#pragma unroll
    for (int i = 0; i < 4; i++) {
      int row = wr + i * 16 + c;
      af[i] = *(const short8*)(&As[row * 32 + (q ^ xsw(row)) * 8]);
    }
#pragma unroll
    for (int j = 0; j < 2; j++) {
      int row = wc + j * 16 + c;
      bfv[j] = *(const short8*)(&Bs[row * 32 + (q ^ xsw(row)) * 8]);
    }
#pragma unroll
    for (int i = 0; i < 4; i++)
#pragma unroll
      for (int j = 0; j < 2; j++)
        acc[i][j] = MFMA16(af[i], bfv[j], acc[i][j]);
  }

#pragma unroll
  for (int i = 0; i < 4; i++) {
    int gm0 = m0 + wr + i * 16 + q * 4;
#pragma unroll
    for (int j = 0; j < 2; j++) {
      int gn = n0 + wc + j * 16 + c;
      float bb = bias[gn];
#pragma unroll
      for (int r = 0; r < 4; r++)
        Out[(size_t)(gm0 + r) * 512 + gn] = acc[i][j][r] + bb;
    }
  }
}

// ---------------- barrier-free flash attention, 32-row waves x kv-split ----------------
// WG = 4 waves: wave (qc, kvh) handles q-rows [bx*64 + qc*32, +32) over kv
// half kvh (kt in [kvh*4, kvh*4+4)). Per kt: S = QK^T (Q pre-scaled) -> exp2
// -> wave-private LDS P -> PV. One barrier total: kv-half partial combine.
__global__ __launch_bounds__(256, 4) void attn_kernel(const unsigned short* __restrict__ Qh,
                                                      const unsigned short* __restrict__ Kh,
                                                      const unsigned short* __restrict__ Vt,
                                                      const unsigned char* __restrict__ codesP,
                                                      unsigned short* __restrict__ AO) {
  __shared__ __align__(16) unsigned short P[4][32 * 132];   // 33 KB, wave-private regions
  __shared__ float rsx[2][32];
  const int tid = threadIdx.x;
  const int lane = tid & 63;
  const int wave = tid >> 6;
  const int c = lane & 15;
  const int q = lane >> 4;
  const int bh = blockIdx.y;
  const int b = bh >> 3;
  const int h = bh & 7;
  const size_t base = (size_t)bh << 16;
  const int qc = wave >> 1;          // q-chunk within WG
  const int kvh = wave & 1;          // kv half
  const int rbase = blockIdx.x * 64 + qc * 32;
  const int rg = rbase >> 5;
  unsigned short* Pw = &P[wave][0];

  // Q A-fragments for both 16-row stripes (pre-scaled by QSCALE)
  short8 aq[2][2];
#pragma unroll
  for (int st = 0; st < 2; st++)
#pragma unroll
    for (int kk = 0; kk < 2; kk++)
      aq[st][kk] = *(const short8*)(Qh + base + (size_t)(rbase + st * 16 + c) * 64 + kk * 32 + q * 8);

  const unsigned char* cbt = codesP + (size_t)(b * 32 + rg) * 32768 + lane * 64;
  const unsigned short* Kb = Kh + base;
  const unsigned short* Vb = Vt + base;

  float rs[2][4];
#pragma unroll
  for (int st = 0; st < 2; st++)
#pragma unroll
    for (int r = 0; r < 4; r++) rs[st][r] = 0.0f;
  floatx4 o[2][4];
#pragma unroll
  for (int st = 0; st < 2; st++)
#pragma unroll
    for (int ci = 0; ci < 4; ci++) o[st][ci] = (floatx4)(0.0f);

  for (int kt = kvh * 4; kt < kvh * 4 + 4; kt++) {
    // ---- QK^T: S[2 stripes][8 col-tiles], K frags straight from global ----
    const unsigned short* Kt = Kb + (size_t)kt * 128 * 64;
    floatx4 s[2][8];
#pragma unroll
    for (int ci = 0; ci < 8; ci++) { s[0][ci] = (floatx4)(0.0f); s[1][ci] = (floatx4)(0.0f); }
#pragma unroll
    for (int ci = 0; ci < 8; ci++)
#pragma unroll
      for (int kk = 0; kk < 2; kk++) {
        short8 bk = *(const short8*)(Kt + (size_t)(ci * 16 + c) * 64 + kk * 32 + q * 8);
        s[0][ci] = MFMA16(aq[0][kk], bk, s[0][ci]);
        s[1][ci] = MFMA16(aq[1][kk], bk, s[1][ci]);
      }
    // ---- codes: 64 bytes/lane, pre-permuted, 4 coalesced dwordx4 ----
    const unsigned char* cp = cbt + (size_t)kt * 4096;
    uint4 w0 = *(const uint4*)(cp);
    uint4 w1 = *(const uint4*)(cp + 16);
    uint4 w2 = *(const uint4*)(cp + 32);
    uint4 w3 = *(const uint4*)(cp + 48);
    unsigned cv[16] = {w0.x, w0.y, w0.z, w0.w, w1.x, w1.y, w1.z, w1.w,
                       w2.x, w2.y, w2.z, w2.w, w3.x, w3.y, w3.z, w3.w};
    // ---- exp epilogue -> wave-private P + register row sums ----
#pragma unroll
    for (int st = 0; st < 2; st++)
#pragma unroll
      for (int ci = 0; ci < 8; ci++)
#pragma unroll
        for (int r = 0; r < 4; r++) {
          int bidx = st * 32 + ci * 4 + r;                       // compile-time
          int code = (cv[bidx >> 2] >> ((bidx & 3) * 8)) & 0xff;
          float e = (h >= code) ? exp2f(s[st][ci][r]) : 0.0f;
          rs[st][r] += e;
          Pw[(st * 16 + q * 4 + r) * 132 + ci * 16 + c] = f2bf(e);
        }
    // ---- PV: wave reads back its own P (lgkmcnt ordering, no barrier) ----
#pragma unroll
    for (int ch = 0; ch < 4; ch++) {
      short8 ap0 = *(const short8*)(&Pw[(size_t)c * 132 + ch * 32 + q * 8]);
      short8 ap1 = *(const short8*)(&Pw[(size_t)(16 + c) * 132 + ch * 32 + q * 8]);
#pragma unroll
      for (int ci = 0; ci < 4; ci++) {
        short8 bv = *(const short8*)(Vb + (size_t)(ci * 16 + c) * 1024 + kt * 128 + ch * 32 + q * 8);
        o[0][ci] = MFMA16(ap0, bv, o[0][ci]);
        o[1][ci] = MFMA16(ap1, bv, o[1][ci]);
      }
    }
  }

  // ---- intra-wave row-sum reduction over the 16 c-lanes ----
#pragma unroll
  for (int st = 0; st < 2; st++)
#pragma unroll
    for (int r = 0; r < 4; r++) {
      float v = rs[st][r];
      v += __shfl_xor(v, 1); v += __shfl_xor(v, 2);
      v += __shfl_xor(v, 4); v += __shfl_xor(v, 8);
      rs[st][r] = v;   // full kv-half sum for row st*16 + q*4 + r
    }

  // ---- kv-half combine through wave (qc,1)'s P region ----
  float* dump = (float*)&P[qc * 2 + 1][0];
  if (kvh == 1) {
#pragma unroll
    for (int st = 0; st < 2; st++)
#pragma unroll
      for (int ci = 0; ci < 4; ci++)
        *(floatx4*)(dump + lane * 32 + (st * 4 + ci) * 4) = o[st][ci];
    if (c == 0) {
#pragma unroll
      for (int st = 0; st < 2; st++)
#pragma unroll
        for (int r = 0; r < 4; r++) rsx[qc][st * 16 + q * 4 + r] = rs[st][r];
    }
  }
  __syncthreads();
  if (kvh == 0) {
    float inv[2][4];
#pragma unroll
    for (int st = 0; st < 2; st++)
#pragma unroll
      for (int ci = 0; ci < 4; ci++)
        o[st][ci] += *(const floatx4*)(dump + lane * 32 + (st * 4 + ci) * 4);
#pragma unroll
    for (int st = 0; st < 2; st++)
#pragma unroll
      for (int r = 0; r < 4; r++)
        inv[st][r] = 1.0f / (rs[st][r] + rsx[qc][st * 16 + q * 4 + r]);
#pragma unroll
    for (int st = 0; st < 2; st++)
#pragma unroll
      for (int r = 0; r < 4; r++) {
        int n = rbase + st * 16 + q * 4 + r;
        size_t ob = ((size_t)((b << 10) + n)) * 512 + h * 64;
#pragma unroll
        for (int ci = 0; ci < 4; ci++)
          AO[ob + ci * 16 + c] = f2bf(o[st][ci][r] * inv[st][r]);
      }
  }
}

// ---------------- launcher ----------------
extern "C" void kernel_launch(void* const* d_in, const int* in_sizes, int n_in,
                              void* d_out, int out_size, void* d_ws, size_t ws_size,
                              hipStream_t stream) {
  const float* query = (const float*)d_in[0];
  const float* key_  = (const float*)d_in[1];
  const float* value = (const float*)d_in[2];
  const float* dist  = (const float*)d_in[3];
  const int*   mask  = (const int*)d_in[4];
  const float* Wq = (const float*)d_in[5];
  const float* bq = (const float*)d_in[6];
  const float* Wk = (const float*)d_in[7];
  const float* bk = (const float*)d_in[8];
  const float* Wv = (const float*)d_in[9];
  const float* bv = (const float*)d_in[10];
  const float* Wo = (const float*)d_in[11];
  const float* bo = (const float*)d_in[12];

  char* ws = (char*)d_ws;
  size_t off = 0;
  auto alloc = [&](size_t bytes) -> char* {
    char* p = ws + off;
    off += (bytes + 255) & ~(size_t)255;
    return p;
  };
  const size_t NQKV = 8192ull * 512;
  unsigned short* qb   = (unsigned short*)alloc(NQKV * 2);
  unsigned short* kb   = (unsigned short*)alloc(NQKV * 2);
  unsigned short* vb   = (unsigned short*)alloc(NQKV * 2);
  unsigned short* wq16 = (unsigned short*)alloc(512ull * 512 * 2);
  unsigned short* wk16 = (unsigned short*)alloc(512ull * 512 * 2);
  unsigned short* wv16 = (unsigned short*)alloc(512ull * 512 * 2);
  unsigned short* wo16 = (unsigned short*)alloc(512ull * 512 * 2);
  unsigned short* Qh = (unsigned short*)alloc(NQKV * 2);
  unsigned short* Kh = (unsigned short*)alloc(NQKV * 2);
  unsigned short* Vt = (unsigned short*)alloc(NQKV * 2);
  unsigned short* AO = (unsigned short*)alloc(NQKV * 2);
  unsigned char*  codesP = (unsigned char*)alloc(8ull * 1024 * 1024);

  prep_kernel<<<21504, 256, 0, stream>>>(query, key_, value, Wq, Wk, Wv, Wo, dist, mask,
                                         qb, kb, vb, wq16, wk16, wv16, wo16, codesP);
  qkv_gemm<<<dim3(64, 4, 3), 256, 0, stream>>>(qb, kb, vb, wq16, wk16, wv16,
                                               bq, bk, bv, Qh, Kh, Vt);
  attn_kernel<<<dim3(16, 64), 256, 0, stream>>>(Qh, Kh, Vt, codesP, AO);
  out_gemm<<<dim3(64, 8), 256, 0, stream>>>(AO, wo16, bo, (float*)d_out);
}